// Round 1
// 548.709 us; speedup vs baseline: 1.1335x; 1.1335x over previous
//
#include <hip/hip_runtime.h>
#include <hip/hip_bf16.h>
#include <cstdint>
#include <cstddef>

// Problem constants: B=128, H=1024, L=256, N=64
typedef __bf16 bf16x8 __attribute__((ext_vector_type(8)));
typedef float  f32x4  __attribute__((ext_vector_type(4)));
typedef unsigned short u16x8 __attribute__((ext_vector_type(8)));

__device__ __forceinline__ unsigned short f2bf(float f) {
    unsigned u = __builtin_bit_cast(unsigned, f);
    u += 0x7fffu + ((u >> 16) & 1u);          // RNE
    return (unsigned short)(u >> 16);
}
__device__ __forceinline__ float bf2f(unsigned short u) {
    unsigned v = ((unsigned)u) << 16;
    return __builtin_bit_cast(float, v);
}
__device__ __forceinline__ float gelu_tanh(float x) {
    // jax.nn.gelu default (approximate=True)
    float z = 0.7978845608028654f * (x + 0.044715f * x * x * x);
    float e = __expf(2.0f * z);
    float t = 1.0f - 2.0f / (e + 1.0f);       // tanh(z)
    return 0.5f * x * (1.0f + t);
}

// =====================================================================
// NEW PATH: conv as Toeplitz MFMA GEMM (bf16 hi/lo 3-term split)
// =====================================================================

// ---- K1: S4D kernel k[h][t] -> Toeplitz delta-tiles in MFMA chunk layout ----
// Per h: 16 delta-tiles (delta = 16*d), each 16 rows(m) x 32 k(kk), chunked as
// [q4 0..3][m 0..15] 16B granules, elem e: value kk[16d + m - (q4*8+e)] (0 if <0),
// with D_h folded onto the diagonal (idx==0). hi at +0, lo at +8192 ushorts.
__global__ void k_build(const float* __restrict__ log_dt,
                        const float* __restrict__ arl,
                        const float* __restrict__ aim,
                        const float* __restrict__ cre,
                        const float* __restrict__ cim,
                        const float* __restrict__ Dp,
                        unsigned short* __restrict__ Tg) {
    __shared__ float sRe[64], sIm[64], sCr[64], sCi[64];
    __shared__ float kk[256];
    const int h = blockIdx.x;
    const int t = threadIdx.x;
    if (t < 64) {
        float dt  = expf(log_dt[h]);
        float ar  = -expf(arl[h * 64 + t]);
        float ai  = aim[h * 64 + t];
        float dre = ar * dt, dim = ai * dt;
        float er  = expf(dre);
        float s, c;
        sincosf(dim, &s, &c);
        float em1r = er * c - 1.0f, em1i = er * s;   // exp(dtA)-1
        float cr = cre[h * 64 + t], ci = cim[h * 64 + t];
        float pr = cr * em1r - ci * em1i;            // C*(exp(dtA)-1)
        float pi = cr * em1i + ci * em1r;
        float inv = 1.0f / (ar * ar + ai * ai);      // /A = *conj(A)/|A|^2
        sCr[t] = (pr * ar + pi * ai) * inv;
        sCi[t] = (pi * ar - pr * ai) * inv;
        sRe[t] = dre; sIm[t] = dim;
    }
    __syncthreads();
    float acc = 0.0f;
    const float tf = (float)t;
    #pragma unroll 8
    for (int n = 0; n < 64; n++) {
        float er = expf(sRe[n] * tf);
        float s, c;
        sincosf(sIm[n] * tf, &s, &c);
        acc += sCr[n] * er * c - sCi[n] * er * s;    // Re(C_disc * exp(dtA*t))
    }
    kk[t] = 2.0f * acc;
    __syncthreads();
    const float Dh = Dp[h];
    unsigned short* dst = Tg + (size_t)h * 16384;
    for (int c = t; c < 1024; c += 256) {            // c = d*64 + q4*16 + m
        const int d = c >> 6, q4 = (c >> 4) & 3, mm = c & 15;
        u16x8 hv, lv;
        #pragma unroll
        for (int e = 0; e < 8; e++) {
            const int idx = 16 * d + mm - (q4 * 8 + e);
            float v = (idx >= 0) ? kk[idx] : 0.0f;
            if (idx == 0) v += Dh;                   // skip connection on diagonal
            unsigned short hb = f2bf(v);
            hv[e] = hb;
            lv[e] = f2bf(v - bf2f(hb));
        }
        *(u16x8*)(dst + c * 8)        = hv;          // hi
        *(u16x8*)(dst + 8192 + c * 8) = lv;          // lo
    }
}

// ---- K2: conv via MFMA. 1 block per h, 4 waves. C[b(row/A), l(col/B)].
// A = X (b rows, k=j), staged fp32->bf16 hi/lo in LDS, double-buffered per k-tile.
// B = T delta-tiles (l rows, k=j) from LDS (loaded once via global_load_lds).
// 3-term: Xh*Th + Xl*Th + Xh*Tl  (error ~2^-17).
// Wave w owns l-16-tiles {w, w+4, w+8, w+12}; tile (i,jt) active iff i >= 2*jt.
__global__ __launch_bounds__(256, 2)
void conv_mfma(const float* __restrict__ x,
               const unsigned short* __restrict__ Tg,
               unsigned short* __restrict__ yt2) {
    __shared__ __align__(16) unsigned short smem[32768];  // 64 KB
    // [0,16384): T (hi 8192, lo 8192)  |  [16384+buf*8192): X buf (hi 4096, lo 4096)
    const int h = blockIdx.x, tid = threadIdx.x;
    const int w = tid >> 6, lane = tid & 63, m = lane & 15, q4 = lane >> 4;

    // load T tiles (32 KB linear)
    {
        const unsigned short* tg = Tg + (size_t)h * 16384;
        #pragma unroll
        for (int i = 0; i < 8; i++) {
            int q = i * 256 + tid;
            __builtin_amdgcn_global_load_lds(
                (const __attribute__((address_space(1))) void*)(tg + q * 8),
                (__attribute__((address_space(3))) void*)(smem + q * 8), 16, 0, 0);
        }
    }

    // staging geometry: thread -> (b = tid>>1, j-half = (tid&1)*16)
    const int sb = tid >> 1;
    const float* xrow = x + (((size_t)(sb * 1024 + h)) << 8) + (tid & 1) * 16;

    // stage k-tile 0 into buf0
    {
        float4 v0 = *(const float4*)(xrow + 0);
        float4 v1 = *(const float4*)(xrow + 4);
        float4 v2 = *(const float4*)(xrow + 8);
        float4 v3 = *(const float4*)(xrow + 12);
        unsigned short* Xn = smem + 16384;
        const int qb = (tid & 1) * 2;
        #pragma unroll
        for (int s = 0; s < 4; s++) {
            float4 v = (s == 0) ? v0 : (s == 1) ? v1 : (s == 2) ? v2 : v3;
            const int q = qb + (s >> 1), off = (s & 1) * 4;
            ushort4 hv, lv;
            hv.x = f2bf(v.x); lv.x = f2bf(v.x - bf2f(hv.x));
            hv.y = f2bf(v.y); lv.y = f2bf(v.y - bf2f(hv.y));
            hv.z = f2bf(v.z); lv.z = f2bf(v.z - bf2f(hv.z));
            hv.w = f2bf(v.w); lv.w = f2bf(v.w - bf2f(hv.w));
            *(ushort4*)(Xn + (q * 128 + sb) * 8 + off)        = hv;
            *(ushort4*)(Xn + 4096 + (q * 128 + sb) * 8 + off) = lv;
        }
    }

    f32x4 acc[8][4];
    #pragma unroll
    for (int a = 0; a < 8; a++)
        #pragma unroll
        for (int b = 0; b < 4; b++) acc[a][b] = (f32x4){0.f, 0.f, 0.f, 0.f};

    __syncthreads();   // T loaded (vmcnt drained) + tile0 staged

    const int fi = (q4 * 16 + m) * 8;   // T-frag chunk offset within a tile (ushorts)

    #pragma unroll 1
    for (int jt = 0; jt < 8; jt++) {
        const unsigned short* Xb = smem + 16384 + (jt & 1) * 8192;
        // prefetch next k-tile's x (global) early
        float4 p0, p1, p2, p3;
        if (jt < 7) {
            const float* xp = xrow + (jt + 1) * 32;
            p0 = *(const float4*)(xp + 0);
            p1 = *(const float4*)(xp + 4);
            p2 = *(const float4*)(xp + 8);
            p3 = *(const float4*)(xp + 12);
        }
        // T fragments for this wave's active tiles
        const int j2 = jt << 1;
        const bool a0 = (w      >= j2);
        const bool a1 = (w + 4  >= j2);
        const bool a2 = (w + 8  >= j2);
        const bool a3 = (w + 12 >= j2);
        bf16x8 th0, tl0, th1, tl1, th2, tl2, th3, tl3;
        if (a0) { int d = w      - j2; th0 = *(const bf16x8*)(smem + d * 512 + fi); tl0 = *(const bf16x8*)(smem + 8192 + d * 512 + fi); }
        if (a1) { int d = w + 4  - j2; th1 = *(const bf16x8*)(smem + d * 512 + fi); tl1 = *(const bf16x8*)(smem + 8192 + d * 512 + fi); }
        if (a2) { int d = w + 8  - j2; th2 = *(const bf16x8*)(smem + d * 512 + fi); tl2 = *(const bf16x8*)(smem + 8192 + d * 512 + fi); }
        if (a3) { int d = w + 12 - j2; th3 = *(const bf16x8*)(smem + d * 512 + fi); tl3 = *(const bf16x8*)(smem + 8192 + d * 512 + fi); }
        #pragma unroll
        for (int fb = 0; fb < 8; fb++) {
            const int xo = (q4 * 128 + fb * 16 + m) * 8;
            bf16x8 xh = *(const bf16x8*)(Xb + xo);
            bf16x8 xl = *(const bf16x8*)(Xb + 4096 + xo);
            if (a0) { acc[fb][0] = __builtin_amdgcn_mfma_f32_16x16x32_bf16(xh, th0, acc[fb][0], 0, 0, 0);
                      acc[fb][0] = __builtin_amdgcn_mfma_f32_16x16x32_bf16(xl, th0, acc[fb][0], 0, 0, 0);
                      acc[fb][0] = __builtin_amdgcn_mfma_f32_16x16x32_bf16(xh, tl0, acc[fb][0], 0, 0, 0); }
            if (a1) { acc[fb][1] = __builtin_amdgcn_mfma_f32_16x16x32_bf16(xh, th1, acc[fb][1], 0, 0, 0);
                      acc[fb][1] = __builtin_amdgcn_mfma_f32_16x16x32_bf16(xl, th1, acc[fb][1], 0, 0, 0);
                      acc[fb][1] = __builtin_amdgcn_mfma_f32_16x16x32_bf16(xh, tl1, acc[fb][1], 0, 0, 0); }
            if (a2) { acc[fb][2] = __builtin_amdgcn_mfma_f32_16x16x32_bf16(xh, th2, acc[fb][2], 0, 0, 0);
                      acc[fb][2] = __builtin_amdgcn_mfma_f32_16x16x32_bf16(xl, th2, acc[fb][2], 0, 0, 0);
                      acc[fb][2] = __builtin_amdgcn_mfma_f32_16x16x32_bf16(xh, tl2, acc[fb][2], 0, 0, 0); }
            if (a3) { acc[fb][3] = __builtin_amdgcn_mfma_f32_16x16x32_bf16(xh, th3, acc[fb][3], 0, 0, 0);
                      acc[fb][3] = __builtin_amdgcn_mfma_f32_16x16x32_bf16(xl, th3, acc[fb][3], 0, 0, 0);
                      acc[fb][3] = __builtin_amdgcn_mfma_f32_16x16x32_bf16(xh, tl3, acc[fb][3], 0, 0, 0); }
        }
        // write staged tile jt+1 (other buffer; readers of it finished pre-barrier)
        if (jt < 7) {
            unsigned short* Xn = smem + 16384 + ((jt + 1) & 1) * 8192;
            const int qb = (tid & 1) * 2;
            #pragma unroll
            for (int s = 0; s < 4; s++) {
                float4 v = (s == 0) ? p0 : (s == 1) ? p1 : (s == 2) ? p2 : p3;
                const int q = qb + (s >> 1), off = (s & 1) * 4;
                ushort4 hv, lv;
                hv.x = f2bf(v.x); lv.x = f2bf(v.x - bf2f(hv.x));
                hv.y = f2bf(v.y); lv.y = f2bf(v.y - bf2f(hv.y));
                hv.z = f2bf(v.z); lv.z = f2bf(v.z - bf2f(hv.z));
                hv.w = f2bf(v.w); lv.w = f2bf(v.w - bf2f(hv.w));
                *(ushort4*)(Xn + (q * 128 + sb) * 8 + off)        = hv;
                *(ushort4*)(Xn + 4096 + (q * 128 + sb) * 8 + off) = lv;
            }
        }
        __syncthreads();
    }

    // epilogue: gelu + bf16, bounce through LDS (stride 136) for 64B-line stores.
    // pass p covers l in [p*128, p*128+128): wave tiles ti = 2p, 2p+1.
    const size_t ybase = (size_t)h * 32768;
    #pragma unroll
    for (int p = 0; p < 2; p++) {
        #pragma unroll
        for (int tt = 0; tt < 2; tt++) {
            const int ti = p * 2 + tt;
            const int lr = (w + 4 * ti) * 16 + m - p * 128;   // 0..127
            #pragma unroll
            for (int fb = 0; fb < 8; fb++) {
                #pragma unroll
                for (int rg = 0; rg < 4; rg++) {
                    const int b = fb * 16 + q4 * 4 + rg;
                    smem[b * 136 + lr] = f2bf(gelu_tanh(acc[fb][ti][rg]));
                }
            }
        }
        __syncthreads();
        #pragma unroll
        for (int bb = 0; bb < 4; bb++) {
            const int bp = bb * 32 + (tid >> 3);
            #pragma unroll
            for (int s = 0; s < 2; s++) {
                const int chk = (tid & 7) + 8 * s;
                u16x8 v = *(const u16x8*)(smem + bp * 136 + chk * 8);
                *(u16x8*)(yt2 + ybase + (size_t)bp * 256 + p * 128 + chk * 8) = v;
            }
        }
        __syncthreads();
    }
}

// ---- K3: transpose yt2[h][m] -> yt[m][h] (64x64 tiles, XOR-swizzled LDS) ----
__global__ void transp(const unsigned short* __restrict__ yt2,
                       unsigned short* __restrict__ yt) {
    __shared__ __align__(16) unsigned short tl[4096];   // 64 rows(h) x 64 (m), chunk-swizzled
    const int tid = threadIdx.x;
    const int m0 = blockIdx.x * 64, h0 = blockIdx.y * 64;
    {
        const int r0 = tid >> 3, ch = tid & 7;
        #pragma unroll
        for (int rr = 0; rr < 64; rr += 32) {
            const int r = r0 + rr;
            u16x8 v = *(const u16x8*)(yt2 + (size_t)(h0 + r) * 32768 + m0 + ch * 8);
            const int pch = ch ^ (r & 7) ^ ((r >> 3) & 7);
            *(u16x8*)(tl + r * 64 + pch * 8) = v;
        }
    }
    __syncthreads();
    {
        const int hc = tid & 7;
        #pragma unroll
        for (int mmr = 0; mmr < 64; mmr += 32) {
            const int mm = (tid >> 3) + mmr;
            u16x8 o;
            #pragma unroll
            for (int e = 0; e < 8; e++) {
                const int hh = hc * 8 + e;
                const int pm = (((mm >> 3) ^ (hh & 7) ^ ((hh >> 3) & 7)) << 3) + (mm & 7);
                o[e] = tl[hh * 64 + pm];
            }
            *(u16x8*)(yt + (size_t)(m0 + mm) * 1024 + h0 + hc * 8) = o;
        }
    }
}

// =====================================================================
// SHARED: W pack + GEMM+GLU (unchanged — control for this round)
// =====================================================================
__global__ void pack_w(const float* __restrict__ W, unsigned short* __restrict__ Wp) {
    const int p  = blockIdx.x;                 // 0..2047
    const int rt = p >> 7, r = p & 127;
    const int g  = (r < 64) ? (rt * 64 + r) : (1024 + rt * 64 + (r - 64));
    const int t  = threadIdx.x;                // 0..255
    const float4 v = *(const float4*)(W + (size_t)g * 1024 + t * 4);
    ushort4 o;
    o.x = f2bf(v.x); o.y = f2bf(v.y); o.z = f2bf(v.z); o.w = f2bf(v.w);
    *(ushort4*)(Wp + (size_t)p * 1024 + t * 4) = o;
}

__global__ __launch_bounds__(256, 2)
void gemm_glu(const unsigned short* __restrict__ yt,
              const unsigned short* __restrict__ Wp,
              const float* __restrict__ bo,
              float* __restrict__ out) {
    __shared__ __align__(16) unsigned char smem[24576];
    unsigned char* sA = smem;                  // 256 c x 32 k bf16, [k8][c] 16B chunks
    unsigned char* sB = smem + 16384;          // 128 p x 32 k bf16, [k8][p]
    const int rt  = blockIdx.x;                // 0..15 (64 output h per tile)
    const int b   = blockIdx.y;                // 0..127
    const int tid = threadIdx.x;
    const int w = tid >> 6, lane = tid & 63, m = lane & 15, q4 = lane >> 4;

    f32x4 acc[4][8];
    #pragma unroll
    for (int fr = 0; fr < 4; fr++)
        #pragma unroll
        for (int fc = 0; fc < 8; fc++) acc[fr][fc] = (f32x4){0.f, 0.f, 0.f, 0.f};

    const size_t ybase = ((size_t)b) << 18;            // b*256*1024 (elements)
    const size_t wbase = ((size_t)rt) * 128 * 1024;

    for (int k0 = 0; k0 < 1024; k0 += 32) {
        #pragma unroll
        for (int t8 = 0; t8 < 4; t8++) {               // A: 1024 16B chunks
            int q = t8 * 256 + tid;
            int k8 = q >> 8, c = q & 255;
            const unsigned short* gp = yt + ybase + (size_t)c * 1024 + k0 + k8 * 8;
            __builtin_amdgcn_global_load_lds((const __attribute__((address_space(1))) void*)gp,
                                             (__attribute__((address_space(3))) void*)(sA + q * 16),
                                             16, 0, 0);
        }
        #pragma unroll
        for (int t8 = 0; t8 < 2; t8++) {               // B: 512 16B chunks
            int q = t8 * 256 + tid;
            int k8 = q >> 7, p = q & 127;
            const unsigned short* gp = Wp + wbase + (size_t)p * 1024 + k0 + k8 * 8;
            __builtin_amdgcn_global_load_lds((const __attribute__((address_space(1))) void*)gp,
                                             (__attribute__((address_space(3))) void*)(sB + q * 16),
                                             16, 0, 0);
        }
        __builtin_amdgcn_s_waitcnt(0x0f70);            // vmcnt(0)
        __syncthreads();

        bf16x8 aF[4];
        #pragma unroll
        for (int fr = 0; fr < 4; fr++)
            aF[fr] = *(const bf16x8*)(sA + ((q4 * 256 + w * 64 + fr * 16 + m) << 4));
        #pragma unroll
        for (int fc = 0; fc < 8; fc++) {
            bf16x8 bF = *(const bf16x8*)(sB + ((q4 * 128 + fc * 16 + m) << 4));
            #pragma unroll
            for (int fr = 0; fr < 4; fr++)
                acc[fr][fc] = __builtin_amdgcn_mfma_f32_16x16x32_bf16(aF[fr], bF, acc[fr][fc], 0, 0, 0);
        }
        __syncthreads();
    }

    // epilogue: val = (a + b_a) * sigmoid(gate + b_g); direct stores
    const size_t orow = ((size_t)(b * 1024 + rt * 64)) << 8;   // *256
    const int cbase = w * 64;
    #pragma unroll
    for (int fc = 0; fc < 4; fc++) {
        float boa = bo[rt * 64 + fc * 16 + m];
        float bog = bo[1024 + rt * 64 + fc * 16 + m];
        #pragma unroll
        for (int fr = 0; fr < 4; fr++) {
            #pragma unroll
            for (int rg = 0; rg < 4; rg++) {
                float av = acc[fr][fc][rg] + boa;
                float gv = acc[fr][fc + 4][rg] + bog;
                float val = av / (1.0f + __expf(-gv));
                out[orow + (((size_t)(fc * 16 + m)) << 8) + cbase + fr * 16 + q4 * 4 + rg] = val;
            }
        }
    }
}

// =====================================================================
// OLD PATH (fallback if workspace too small): original k_kernel + conv
// =====================================================================
__global__ void k_kernel(const float* __restrict__ log_dt,
                         const float* __restrict__ arl,
                         const float* __restrict__ aim,
                         const float* __restrict__ cre,
                         const float* __restrict__ cim,
                         float* __restrict__ kout) {
    __shared__ float sRe[64], sIm[64], sCr[64], sCi[64];
    const int h = blockIdx.x;
    const int t = threadIdx.x;
    if (t < 64) {
        float dt  = expf(log_dt[h]);
        float ar  = -expf(arl[h * 64 + t]);
        float ai  = aim[h * 64 + t];
        float dre = ar * dt, dim = ai * dt;
        float er  = expf(dre);
        float s, c;
        sincosf(dim, &s, &c);
        float em1r = er * c - 1.0f, em1i = er * s;
        float cr = cre[h * 64 + t], ci = cim[h * 64 + t];
        float pr = cr * em1r - ci * em1i;
        float pi = cr * em1i + ci * em1r;
        float inv = 1.0f / (ar * ar + ai * ai);
        sCr[t] = (pr * ar + pi * ai) * inv;
        sCi[t] = (pi * ar - pr * ai) * inv;
        sRe[t] = dre; sIm[t] = dim;
    }
    __syncthreads();
    float acc = 0.0f;
    const float tf = (float)t;
    #pragma unroll 8
    for (int n = 0; n < 64; n++) {
        float er = expf(sRe[n] * tf);
        float s, c;
        sincosf(sIm[n] * tf, &s, &c);
        acc += sCr[n] * er * c - sCi[n] * er * s;
    }
    kout[h * 256 + t] = 2.0f * acc;
}

__global__ void conv_kernel(const float* __restrict__ x,
                            const float* __restrict__ kg,
                            const float* __restrict__ D,
                            unsigned short* __restrict__ yt) {
    __shared__ float xt[256 * 32];
    __shared__ float kt[256 * 32];
    const int b     = blockIdx.y;
    const int hbase = blockIdx.x * 32;
    const int tid   = threadIdx.x;
    {
        const int h  = tid & 31;
        const int c0 = tid >> 5;
        #pragma unroll
        for (int t8 = 0; t8 < 8; t8++) {
            int c4 = c0 + t8 * 8;
            float4 xv = *(const float4*)(x + (((size_t)(b * 1024 + hbase + h)) << 8) + c4 * 4);
            float4 kv = *(const float4*)(kg + (((size_t)(hbase + h)) << 8) + c4 * 4);
            int l = c4 * 4;
            xt[(l + 0) * 32 + h] = xv.x; xt[(l + 1) * 32 + h] = xv.y;
            xt[(l + 2) * 32 + h] = xv.z; xt[(l + 3) * 32 + h] = xv.w;
            kt[(l + 0) * 32 + h] = kv.x; kt[(l + 1) * 32 + h] = kv.y;
            kt[(l + 2) * 32 + h] = kv.z; kt[(l + 3) * 32 + h] = kv.w;
        }
    }
    __syncthreads();

    const int h    = tid & 31;
    const int slot = tid >> 5;
    const float Dh = D[hbase + h];
    int cs[4] = { slot, 15 - slot, 16 + slot, 31 - slot };

    for (int ci = 0; ci < 4; ci++) {
        const int c  = cs[ci];
        const int l0 = c * 8;
        float acc[8];
        #pragma unroll
        for (int i = 0; i < 8; i++) acc[i] = 0.0f;
        float kw[16];
        #pragma unroll
        for (int v = 0; v < 8; v++) kw[8 + v] = kt[(l0 + v) * 32 + h];
        float X[8];
        for (int base = l0; base > 0; base -= 8) {
            #pragma unroll
            for (int v = 0; v < 8; v++) kw[v] = kt[(base - 8 + v) * 32 + h];
            const int jb = l0 - base;
            #pragma unroll
            for (int u = 0; u < 8; u++) X[u] = xt[(jb + u) * 32 + h];
            #pragma unroll
            for (int u = 0; u < 8; u++)
                #pragma unroll
                for (int i = 0; i < 8; i++)
                    acc[i] = fmaf(kw[8 + i - u], X[u], acc[i]);
            #pragma unroll
            for (int v = 0; v < 8; v++) kw[8 + v] = kw[v];
        }
        #pragma unroll
        for (int u = 0; u < 8; u++) X[u] = xt[(l0 + u) * 32 + h];
        #pragma unroll
        for (int u = 0; u < 8; u++)
            #pragma unroll
            for (int i = u; i < 8; i++)
                acc[i] = fmaf(kw[8 + i - u], X[u], acc[i]);
        #pragma unroll
        for (int i = 0; i < 8; i++) {
            float y = acc[i] + Dh * X[i];
            yt[(((size_t)(b * 256 + l0 + i)) << 10) + hbase + h] = f2bf(gelu_tanh(y));
        }
    }
}

// =====================================================================
extern "C" void kernel_launch(void* const* d_in, const int* in_sizes, int n_in,
                              void* d_out, int out_size, void* d_ws, size_t ws_size,
                              hipStream_t stream) {
    const float* x   = (const float*)d_in[0];
    const float* ldt = (const float*)d_in[1];
    const float* arl = (const float*)d_in[2];
    const float* aim = (const float*)d_in[3];
    const float* cre = (const float*)d_in[4];
    const float* cim = (const float*)d_in[5];
    const float* D   = (const float*)d_in[6];
    const float* Wo  = (const float*)d_in[7];
    const float* bo  = (const float*)d_in[8];
    float* out = (float*)d_out;

    // ---- new path layout ----
    // Wp  [0, 4MB)     : 2048 x 1024 bf16
    // Tg  [4MB, 36MB)  : 1024 h x 32KB Toeplitz tiles (dead after conv)
    // yt  [4MB, 68MB)  : 32768 x 1024 bf16 (aliases Tg; written by transp after conv)
    // yt2 [68MB, 132MB): 1024 h x 32768 bf16
    const size_t MB = (size_t)1 << 20;
    const size_t needNew = 132 * MB;

    if (ws_size >= needNew) {
        unsigned short* Wp  = (unsigned short*)d_ws;
        unsigned short* Tg  = (unsigned short*)((char*)d_ws + 4 * MB);
        unsigned short* yt  = (unsigned short*)((char*)d_ws + 4 * MB);
        unsigned short* yt2 = (unsigned short*)((char*)d_ws + 68 * MB);

        k_build  <<<1024, 256, 0, stream>>>(ldt, arl, aim, cre, cim, D, Tg);
        pack_w   <<<2048, 256, 0, stream>>>(Wo, Wp);
        conv_mfma<<<1024, 256, 0, stream>>>(x, Tg, yt2);
        transp   <<<dim3(512, 16), 256, 0, stream>>>(yt2, yt);
        gemm_glu <<<dim3(16, 128), 256, 0, stream>>>(yt, Wp, bo, out);
        return;
    }

    // ---- fallback: previous verified path (needs 69 MB) ----
    const size_t kOff = 0;
    const size_t wOff = (size_t)1 << 20;
    const size_t yOff = wOff + ((size_t)1 << 22);
    const size_t need = yOff + (size_t)128 * 256 * 1024 * 2;
    if (ws_size < need) return;

    float*          kg = (float*)((char*)d_ws + kOff);
    unsigned short* Wp = (unsigned short*)((char*)d_ws + wOff);
    unsigned short* yt = (unsigned short*)((char*)d_ws + yOff);

    k_kernel  <<<1024, 256, 0, stream>>>(ldt, arl, aim, cre, cim, kg);
    pack_w    <<<2048, 256, 0, stream>>>(Wo, Wp);
    conv_kernel<<<dim3(32, 128), 256, 0, stream>>>(x, kg, D, yt);
    gemm_glu  <<<dim3(16, 128), 256, 0, stream>>>(yt, Wp, bo, out);
}

// Round 2
// 441.358 us; speedup vs baseline: 1.4093x; 1.2432x over previous
//
#include <hip/hip_runtime.h>
#include <hip/hip_bf16.h>
#include <cstdint>
#include <cstddef>

// Problem constants: B=128, H=1024, L=256, N=64
typedef __bf16 bf16x8 __attribute__((ext_vector_type(8)));
typedef float  f32x4  __attribute__((ext_vector_type(4)));
typedef unsigned short u16x8 __attribute__((ext_vector_type(8)));

__device__ __forceinline__ unsigned short f2bf(float f) {
    unsigned u = __builtin_bit_cast(unsigned, f);
    u += 0x7fffu + ((u >> 16) & 1u);          // RNE
    return (unsigned short)(u >> 16);
}
__device__ __forceinline__ float bf2f(unsigned short u) {
    unsigned v = ((unsigned)u) << 16;
    return __builtin_bit_cast(float, v);
}
__device__ __forceinline__ float gelu_tanh(float x) {
    // jax.nn.gelu default (approximate=True)
    float z = 0.7978845608028654f * (x + 0.044715f * x * x * x);
    float e = __expf(2.0f * z);
    float t = 1.0f - 2.0f / (e + 1.0f);       // tanh(z)
    return 0.5f * x * (1.0f + t);
}

// ---- K1: S4D kernel k[h][t] -> Toeplitz delta-tiles in MFMA chunk layout ----
__global__ void k_build(const float* __restrict__ log_dt,
                        const float* __restrict__ arl,
                        const float* __restrict__ aim,
                        const float* __restrict__ cre,
                        const float* __restrict__ cim,
                        const float* __restrict__ Dp,
                        unsigned short* __restrict__ Tg) {
    __shared__ float sRe[64], sIm[64], sCr[64], sCi[64];
    __shared__ float kk[256];
    const int h = blockIdx.x;
    const int t = threadIdx.x;
    if (t < 64) {
        float dt  = expf(log_dt[h]);
        float ar  = -expf(arl[h * 64 + t]);
        float ai  = aim[h * 64 + t];
        float dre = ar * dt, dim = ai * dt;
        float er  = expf(dre);
        float s, c;
        sincosf(dim, &s, &c);
        float em1r = er * c - 1.0f, em1i = er * s;   // exp(dtA)-1
        float cr = cre[h * 64 + t], ci = cim[h * 64 + t];
        float pr = cr * em1r - ci * em1i;            // C*(exp(dtA)-1)
        float pi = cr * em1i + ci * em1r;
        float inv = 1.0f / (ar * ar + ai * ai);      // /A = *conj(A)/|A|^2
        sCr[t] = (pr * ar + pi * ai) * inv;
        sCi[t] = (pi * ar - pr * ai) * inv;
        sRe[t] = dre; sIm[t] = dim;
    }
    __syncthreads();
    float acc = 0.0f;
    const float tf = (float)t;
    #pragma unroll 8
    for (int n = 0; n < 64; n++) {
        float er = expf(sRe[n] * tf);
        float s, c;
        sincosf(sIm[n] * tf, &s, &c);
        acc += sCr[n] * er * c - sCi[n] * er * s;    // Re(C_disc * exp(dtA*t))
    }
    kk[t] = 2.0f * acc;
    __syncthreads();
    const float Dh = Dp[h];
    unsigned short* dst = Tg + (size_t)h * 16384;
    for (int c = t; c < 1024; c += 256) {            // c = d*64 + q4*16 + m
        const int d = c >> 6, q4 = (c >> 4) & 3, mm = c & 15;
        u16x8 hv, lv;
        #pragma unroll
        for (int e = 0; e < 8; e++) {
            const int idx = 16 * d + mm - (q4 * 8 + e);
            float v = (idx >= 0) ? kk[idx] : 0.0f;
            if (idx == 0) v += Dh;                   // skip connection on diagonal
            unsigned short hb = f2bf(v);
            hv[e] = hb;
            lv[e] = f2bf(v - bf2f(hb));
        }
        *(u16x8*)(dst + c * 8)        = hv;          // hi
        *(u16x8*)(dst + 8192 + c * 8) = lv;          // lo
    }
}

// ---- K2: conv via MFMA (unchanged from round 1) ----
__global__ __launch_bounds__(256, 2)
void conv_mfma(const float* __restrict__ x,
               const unsigned short* __restrict__ Tg,
               unsigned short* __restrict__ yt2) {
    __shared__ __align__(16) unsigned short smem[32768];  // 64 KB
    const int h = blockIdx.x, tid = threadIdx.x;
    const int w = tid >> 6, lane = tid & 63, m = lane & 15, q4 = lane >> 4;

    {
        const unsigned short* tg = Tg + (size_t)h * 16384;
        #pragma unroll
        for (int i = 0; i < 8; i++) {
            int q = i * 256 + tid;
            __builtin_amdgcn_global_load_lds(
                (const __attribute__((address_space(1))) void*)(tg + q * 8),
                (__attribute__((address_space(3))) void*)(smem + q * 8), 16, 0, 0);
        }
    }

    const int sb = tid >> 1;
    const float* xrow = x + (((size_t)(sb * 1024 + h)) << 8) + (tid & 1) * 16;

    {
        float4 v0 = *(const float4*)(xrow + 0);
        float4 v1 = *(const float4*)(xrow + 4);
        float4 v2 = *(const float4*)(xrow + 8);
        float4 v3 = *(const float4*)(xrow + 12);
        unsigned short* Xn = smem + 16384;
        const int qb = (tid & 1) * 2;
        #pragma unroll
        for (int s = 0; s < 4; s++) {
            float4 v = (s == 0) ? v0 : (s == 1) ? v1 : (s == 2) ? v2 : v3;
            const int q = qb + (s >> 1), off = (s & 1) * 4;
            ushort4 hv, lv;
            hv.x = f2bf(v.x); lv.x = f2bf(v.x - bf2f(hv.x));
            hv.y = f2bf(v.y); lv.y = f2bf(v.y - bf2f(hv.y));
            hv.z = f2bf(v.z); lv.z = f2bf(v.z - bf2f(hv.z));
            hv.w = f2bf(v.w); lv.w = f2bf(v.w - bf2f(hv.w));
            *(ushort4*)(Xn + (q * 128 + sb) * 8 + off)        = hv;
            *(ushort4*)(Xn + 4096 + (q * 128 + sb) * 8 + off) = lv;
        }
    }

    f32x4 acc[8][4];
    #pragma unroll
    for (int a = 0; a < 8; a++)
        #pragma unroll
        for (int b = 0; b < 4; b++) acc[a][b] = (f32x4){0.f, 0.f, 0.f, 0.f};

    __syncthreads();

    const int fi = (q4 * 16 + m) * 8;

    #pragma unroll 1
    for (int jt = 0; jt < 8; jt++) {
        const unsigned short* Xb = smem + 16384 + (jt & 1) * 8192;
        float4 p0, p1, p2, p3;
        if (jt < 7) {
            const float* xp = xrow + (jt + 1) * 32;
            p0 = *(const float4*)(xp + 0);
            p1 = *(const float4*)(xp + 4);
            p2 = *(const float4*)(xp + 8);
            p3 = *(const float4*)(xp + 12);
        }
        const int j2 = jt << 1;
        const bool a0 = (w      >= j2);
        const bool a1 = (w + 4  >= j2);
        const bool a2 = (w + 8  >= j2);
        const bool a3 = (w + 12 >= j2);
        bf16x8 th0, tl0, th1, tl1, th2, tl2, th3, tl3;
        if (a0) { int d = w      - j2; th0 = *(const bf16x8*)(smem + d * 512 + fi); tl0 = *(const bf16x8*)(smem + 8192 + d * 512 + fi); }
        if (a1) { int d = w + 4  - j2; th1 = *(const bf16x8*)(smem + d * 512 + fi); tl1 = *(const bf16x8*)(smem + 8192 + d * 512 + fi); }
        if (a2) { int d = w + 8  - j2; th2 = *(const bf16x8*)(smem + d * 512 + fi); tl2 = *(const bf16x8*)(smem + 8192 + d * 512 + fi); }
        if (a3) { int d = w + 12 - j2; th3 = *(const bf16x8*)(smem + d * 512 + fi); tl3 = *(const bf16x8*)(smem + 8192 + d * 512 + fi); }
        #pragma unroll
        for (int fb = 0; fb < 8; fb++) {
            const int xo = (q4 * 128 + fb * 16 + m) * 8;
            bf16x8 xh = *(const bf16x8*)(Xb + xo);
            bf16x8 xl = *(const bf16x8*)(Xb + 4096 + xo);
            if (a0) { acc[fb][0] = __builtin_amdgcn_mfma_f32_16x16x32_bf16(xh, th0, acc[fb][0], 0, 0, 0);
                      acc[fb][0] = __builtin_amdgcn_mfma_f32_16x16x32_bf16(xl, th0, acc[fb][0], 0, 0, 0);
                      acc[fb][0] = __builtin_amdgcn_mfma_f32_16x16x32_bf16(xh, tl0, acc[fb][0], 0, 0, 0); }
            if (a1) { acc[fb][1] = __builtin_amdgcn_mfma_f32_16x16x32_bf16(xh, th1, acc[fb][1], 0, 0, 0);
                      acc[fb][1] = __builtin_amdgcn_mfma_f32_16x16x32_bf16(xl, th1, acc[fb][1], 0, 0, 0);
                      acc[fb][1] = __builtin_amdgcn_mfma_f32_16x16x32_bf16(xh, tl1, acc[fb][1], 0, 0, 0); }
            if (a2) { acc[fb][2] = __builtin_amdgcn_mfma_f32_16x16x32_bf16(xh, th2, acc[fb][2], 0, 0, 0);
                      acc[fb][2] = __builtin_amdgcn_mfma_f32_16x16x32_bf16(xl, th2, acc[fb][2], 0, 0, 0);
                      acc[fb][2] = __builtin_amdgcn_mfma_f32_16x16x32_bf16(xh, tl2, acc[fb][2], 0, 0, 0); }
            if (a3) { acc[fb][3] = __builtin_amdgcn_mfma_f32_16x16x32_bf16(xh, th3, acc[fb][3], 0, 0, 0);
                      acc[fb][3] = __builtin_amdgcn_mfma_f32_16x16x32_bf16(xl, th3, acc[fb][3], 0, 0, 0);
                      acc[fb][3] = __builtin_amdgcn_mfma_f32_16x16x32_bf16(xh, tl3, acc[fb][3], 0, 0, 0); }
        }
        if (jt < 7) {
            unsigned short* Xn = smem + 16384 + ((jt + 1) & 1) * 8192;
            const int qb = (tid & 1) * 2;
            #pragma unroll
            for (int s = 0; s < 4; s++) {
                float4 v = (s == 0) ? p0 : (s == 1) ? p1 : (s == 2) ? p2 : p3;
                const int q = qb + (s >> 1), off = (s & 1) * 4;
                ushort4 hv, lv;
                hv.x = f2bf(v.x); lv.x = f2bf(v.x - bf2f(hv.x));
                hv.y = f2bf(v.y); lv.y = f2bf(v.y - bf2f(hv.y));
                hv.z = f2bf(v.z); lv.z = f2bf(v.z - bf2f(hv.z));
                hv.w = f2bf(v.w); lv.w = f2bf(v.w - bf2f(hv.w));
                *(ushort4*)(Xn + (q * 128 + sb) * 8 + off)        = hv;
                *(ushort4*)(Xn + 4096 + (q * 128 + sb) * 8 + off) = lv;
            }
        }
        __syncthreads();
    }

    const size_t ybase = (size_t)h * 32768;
    #pragma unroll
    for (int p = 0; p < 2; p++) {
        #pragma unroll
        for (int tt = 0; tt < 2; tt++) {
            const int ti = p * 2 + tt;
            const int lr = (w + 4 * ti) * 16 + m - p * 128;
            #pragma unroll
            for (int fb = 0; fb < 8; fb++) {
                #pragma unroll
                for (int rg = 0; rg < 4; rg++) {
                    const int b = fb * 16 + q4 * 4 + rg;
                    smem[b * 136 + lr] = f2bf(gelu_tanh(acc[fb][ti][rg]));
                }
            }
        }
        __syncthreads();
        #pragma unroll
        for (int bb = 0; bb < 4; bb++) {
            const int bp = bb * 32 + (tid >> 3);
            #pragma unroll
            for (int s = 0; s < 2; s++) {
                const int chk = (tid & 7) + 8 * s;
                u16x8 v = *(const u16x8*)(smem + bp * 136 + chk * 8);
                *(u16x8*)(yt2 + ybase + (size_t)bp * 256 + p * 128 + chk * 8) = v;
            }
        }
        __syncthreads();
    }
}

// ---- K3: transpose yt2[h][m] -> yt[m][h] (unchanged) ----
__global__ void transp(const unsigned short* __restrict__ yt2,
                       unsigned short* __restrict__ yt) {
    __shared__ __align__(16) unsigned short tl[4096];
    const int tid = threadIdx.x;
    const int m0 = blockIdx.x * 64, h0 = blockIdx.y * 64;
    {
        const int r0 = tid >> 3, ch = tid & 7;
        #pragma unroll
        for (int rr = 0; rr < 64; rr += 32) {
            const int r = r0 + rr;
            u16x8 v = *(const u16x8*)(yt2 + (size_t)(h0 + r) * 32768 + m0 + ch * 8);
            const int pch = ch ^ (r & 7) ^ ((r >> 3) & 7);
            *(u16x8*)(tl + r * 64 + pch * 8) = v;
        }
    }
    __syncthreads();
    {
        const int hc = tid & 7;
        #pragma unroll
        for (int mmr = 0; mmr < 64; mmr += 32) {
            const int mm = (tid >> 3) + mmr;
            u16x8 o;
            #pragma unroll
            for (int e = 0; e < 8; e++) {
                const int hh = hc * 8 + e;
                const int pm = (((mm >> 3) ^ (hh & 7) ^ ((hh >> 3) & 7)) << 3) + (mm & 7);
                o[e] = tl[hh * 64 + pm];
            }
            *(u16x8*)(yt + (size_t)(m0 + mm) * 1024 + h0 + hc * 8) = o;
        }
    }
}

// ---- K1b: pack W_out with GLU-pair-interleaved rows for the 256^2 GEMM ------
// Wp row p: g32 = p>>5, r32 = p&31. r32<16 -> a-row (W row g32*16+r32);
// r32>=16 -> gate row (W row 1024 + g32*16 + r32-16). Pairs sit 16 cols apart
// -> both members land in one wave's adjacent fc fragments (lane-local GLU).
__global__ void pack_w2(const float* __restrict__ W, unsigned short* __restrict__ Wp) {
    const int p   = blockIdx.x;                // 0..2047
    const int g32 = p >> 5, r32 = p & 31;
    const int g   = (r32 < 16) ? (g32 * 16 + r32) : (1024 + g32 * 16 + (r32 - 16));
    const int t   = threadIdx.x;               // 0..255
    const float4 v = *(const float4*)(W + (size_t)g * 1024 + t * 4);
    ushort4 o;
    o.x = f2bf(v.x); o.y = f2bf(v.y); o.z = f2bf(v.z); o.w = f2bf(v.w);
    *(ushort4*)(Wp + (size_t)p * 1024 + t * 4) = o;
}

// ---- K4: 256x256-tile deep-pipelined bf16 GEMM + GLU (T2+T3/T4+T5) ---------
// C[32768 m][2048 p] = Y[m][k=1024] x Wp[p][k]^T, 512 thr = 8 waves (2M x 4N),
// BK=64, LDS 128KB double-buffer, prefetch depth 2 K-tiles, vmcnt(8) counted,
// chunk-XOR swizzle c^=(r&7) via inverse-swizzled global src (rule #21).
__global__ __launch_bounds__(512, 2)
void gemm_glu2(const unsigned short* __restrict__ yt,
               const unsigned short* __restrict__ Wp,
               const float* __restrict__ bo,
               float* __restrict__ out) {
    __shared__ __align__(16) unsigned short smem[65536];   // 128 KB
    const int tid = threadIdx.x;
    const int bid = (int)blockIdx.x;
    const int b1  = (bid & 7) * 128 + (bid >> 3);  // XCD swizzle (1024 wgs, 8 XCDs)
    const int bm  = b1 >> 3;                       // 0..127 : rows bm*256 (= batch bm)
    const int bn  = b1 & 3 | (b1 & 7);             // placeholder avoided below
    const int bn_ = b1 & 7;                        // 0..7   : Wp rows bn*256
    const int wid = tid >> 6, lane = tid & 63;
    const int m = lane & 15, q4 = lane >> 4;
    const int wm = wid >> 2, wn = wid & 3;

    const size_t abase = (size_t)bm * 256 * 1024;
    const size_t bbase = (size_t)bn_ * 256 * 1024;

    f32x4 acc[8][4];
    #pragma unroll
    for (int fr = 0; fr < 8; fr++)
        #pragma unroll
        for (int fc = 0; fc < 4; fc++) acc[fr][fc] = (f32x4){0.f, 0.f, 0.f, 0.f};

    auto STAGE = [&](int t) {
        const int bufo = (t & 1) << 15;            // ushort offset (32768 = 64KB)
        const int k0 = t * 64;
        #pragma unroll
        for (int i = 0; i < 4; i++) {              // A: 2048 chunks (256 r x 8 c)
            int q = i * 512 + tid;
            int r = q >> 3, c = (q & 7) ^ (r & 7);
            const unsigned short* gp = yt + abase + (size_t)r * 1024 + k0 + c * 8;
            __builtin_amdgcn_global_load_lds(
                (const __attribute__((address_space(1))) void*)gp,
                (__attribute__((address_space(3))) void*)(smem + bufo + q * 8), 16, 0, 0);
        }
        #pragma unroll
        for (int i = 0; i < 4; i++) {              // B: 2048 chunks
            int q = i * 512 + tid;
            int r = q >> 3, c = (q & 7) ^ (r & 7);
            const unsigned short* gp = Wp + bbase + (size_t)r * 1024 + k0 + c * 8;
            __builtin_amdgcn_global_load_lds(
                (const __attribute__((address_space(1))) void*)gp,
                (__attribute__((address_space(3))) void*)(smem + bufo + 16384 + q * 8), 16, 0, 0);
        }
    };

    STAGE(0);
    STAGE(1);
    asm volatile("s_waitcnt vmcnt(8)" ::: "memory");   // tile 0 landed
    __builtin_amdgcn_s_barrier();

    const int arow0 = wm * 128;
    const int brow0 = wn * 64;

    for (int t = 0; t < 16; t++) {
        const int bufo = (t & 1) << 15;
        bf16x8 af[8][2], bf[4][2];
        #pragma unroll
        for (int fr = 0; fr < 8; fr++) {
            const int r = arow0 + fr * 16 + m;
            #pragma unroll
            for (int ks = 0; ks < 2; ks++) {
                const int c = (ks * 4 + q4) ^ (r & 7);
                af[fr][ks] = *(const bf16x8*)(smem + bufo + r * 64 + c * 8);
            }
        }
        #pragma unroll
        for (int fc = 0; fc < 4; fc++) {
            const int r = brow0 + fc * 16 + m;
            #pragma unroll
            for (int ks = 0; ks < 2; ks++) {
                const int c = (ks * 4 + q4) ^ (r & 7);
                bf[fc][ks] = *(const bf16x8*)(smem + bufo + 16384 + r * 64 + c * 8);
            }
        }
        // all waves must finish reg-loading this buffer before anyone overwrites it
        asm volatile("s_waitcnt lgkmcnt(0)" ::: "memory");
        __builtin_amdgcn_sched_barrier(0);
        __builtin_amdgcn_s_barrier();
        if (t < 14) STAGE(t + 2);                  // overwrite buffer just consumed
        __builtin_amdgcn_s_setprio(1);
        #pragma unroll
        for (int ks = 0; ks < 2; ks++)
            #pragma unroll
            for (int fr = 0; fr < 8; fr++)
                #pragma unroll
                for (int fc = 0; fc < 4; fc++)
                    acc[fr][fc] = __builtin_amdgcn_mfma_f32_16x16x32_bf16(
                        af[fr][ks], bf[fc][ks], acc[fr][fc], 0, 0, 0);
        __builtin_amdgcn_s_setprio(0);
        if (t < 14) asm volatile("s_waitcnt vmcnt(8)" ::: "memory");  // t+1 landed
        else        asm volatile("s_waitcnt vmcnt(0)" ::: "memory");  // drain tail
        __builtin_amdgcn_s_barrier();
    }

    // epilogue: GLU lane-local (a at fc=2*fcp, gate at fc=2*fcp+1), float4 stores
    const size_t outb = ((size_t)bm) << 18;        // bm*1024*256
    const int lbase = wm * 128;
    #pragma unroll
    for (int fcp = 0; fcp < 2; fcp++) {
        const int go = (bn_ * 8 + wn * 2 + fcp) * 16 + m;
        const float boa = bo[go], bog = bo[1024 + go];
        #pragma unroll
        for (int fr = 0; fr < 8; fr++) {
            f32x4 av = acc[fr][2 * fcp];
            f32x4 gv = acc[fr][2 * fcp + 1];
            f32x4 o;
            #pragma unroll
            for (int rg = 0; rg < 4; rg++) {
                float a = av[rg] + boa, g = gv[rg] + bog;
                o[rg] = a / (1.0f + __expf(-g));
            }
            const int l = lbase + fr * 16 + q4 * 4;
            *(f32x4*)(out + outb + (((size_t)go) << 8) + l) = o;
        }
    }
    (void)bn;
}

// =====================================================================
extern "C" void kernel_launch(void* const* d_in, const int* in_sizes, int n_in,
                              void* d_out, int out_size, void* d_ws, size_t ws_size,
                              hipStream_t stream) {
    const float* x   = (const float*)d_in[0];
    const float* ldt = (const float*)d_in[1];
    const float* arl = (const float*)d_in[2];
    const float* aim = (const float*)d_in[3];
    const float* cre = (const float*)d_in[4];
    const float* cim = (const float*)d_in[5];
    const float* D   = (const float*)d_in[6];
    const float* Wo  = (const float*)d_in[7];
    const float* bo  = (const float*)d_in[8];
    float* out = (float*)d_out;

    // Wp  [0, 4MB)     : 2048 x 1024 bf16 (pair-interleaved packing)
    // Tg  [4MB, 36MB)  : 1024 h x 32KB Toeplitz tiles (dead after conv)
    // yt  [4MB, 68MB)  : 32768 x 1024 bf16 (aliases Tg; written by transp)
    // yt2 [68MB, 132MB): 1024 h x 32768 bf16
    const size_t MB = (size_t)1 << 20;
    const size_t need = 132 * MB;
    if (ws_size < need) return;                    // loud failure, no corruption

    unsigned short* Wp  = (unsigned short*)d_ws;
    unsigned short* Tg  = (unsigned short*)((char*)d_ws + 4 * MB);
    unsigned short* yt  = (unsigned short*)((char*)d_ws + 4 * MB);
    unsigned short* yt2 = (unsigned short*)((char*)d_ws + 68 * MB);

    k_build  <<<1024, 256, 0, stream>>>(ldt, arl, aim, cre, cim, D, Tg);
    pack_w2  <<<2048, 256, 0, stream>>>(Wo, Wp);
    conv_mfma<<<1024, 256, 0, stream>>>(x, Tg, yt2);
    transp   <<<dim3(512, 16), 256, 0, stream>>>(yt2, yt);
    gemm_glu2<<<1024, 512, 0, stream>>>(yt, Wp, bo, out);
}